// Round 6
// baseline (1199.830 us; speedup 1.0000x reference)
//
#include <hip/hip_runtime.h>

// Relation_5841155522972 — talking-heads attention, straight-through hard select.
// out[b,i,h*64+d] = v[b, argmax_j n[b,h,i,j], h*64+d],
// n = LayerNorm_h( softmax_j(QK^T/32) mixed by Wt ).
//
// R6: k-register + scalar-q dot engine for both attention passes.
//  K1  qkv_gemm      : fp32 GEMM; q STRAIGHT ([i][h*64+d]), k transposed, V straight.
//  K2a attn_stats_v6 : l = sum_j exp(s) only (no max-sub; |s| small, safe).
//                      Lane = j, k[64] in VGPRs per h, q via uniform s_load.
//                      Zero LDS, zero barriers. Partials per 64-j slice.
//  K2b merge_l       : Rl = 1/sum of the 16 slice partials (deterministic).
//  K2c attn_select_v6: same dot engine -> p = exp(s)*Rl -> ptile (stride 271),
//                      1 barrier, R5-verified mix/LN/argmax + packed atomicMax.
//  K2d gather_v4     : decode key -> gather V rows (R4/R5-verified).
// ws: ~53 MB.

#define FMA4(cc, av, bv) \
  cc.x = fmaf(av, bv.x, cc.x); cc.y = fmaf(av, bv.y, cc.y); \
  cc.z = fmaf(av, bv.z, cc.z); cc.w = fmaf(av, bv.w, cc.w);

__global__ __launch_bounds__(256) void qkv_gemm(
    const float* __restrict__ X, const float* __restrict__ Wq,
    const float* __restrict__ Wkv, float* __restrict__ Q,
    float* __restrict__ kT, float* __restrict__ V)
{
  __shared__ __align__(16) float As[16 * 132];
  __shared__ __align__(16) float Bs[16 * 132];
  __shared__ __align__(16) float tb[128 * 32];

  const int t  = threadIdx.x;
  const int bn = blockIdx.x;
  const int bm = blockIdx.y;
  const int m0 = bm * 128, n0 = bn * 128;
  const int ty = t >> 4, tx = t & 15;

  const float* Wbase = (n0 < 1024) ? Wq : Wkv;
  const int nw0 = (n0 < 1024) ? n0 : (n0 - 1024);

  float4 c2[8][2];
#pragma unroll
  for (int a = 0; a < 8; a++) {
    c2[a][0] = make_float4(0.f, 0.f, 0.f, 0.f);
    c2[a][1] = make_float4(0.f, 0.f, 0.f, 0.f);
  }

  const int lr = t >> 1;
  const int lh = t & 1;

  const float4* As4 = (const float4*)As;
  const float4* Bs4 = (const float4*)Bs;

  for (int kb = 0; kb < 64; kb++) {
    const int k0 = kb * 16;
    __syncthreads();
#pragma unroll
    for (int s = 0; s < 2; s++) {
      const int kk = lh * 8 + s * 4;
      float4 av = *(const float4*)&X[(size_t)(m0 + lr) * 1024 + k0 + kk];
      float4 bv = *(const float4*)&Wbase[(size_t)(nw0 + lr) * 1024 + k0 + kk];
      As[(kk + 0) * 132 + lr] = av.x;
      As[(kk + 1) * 132 + lr] = av.y;
      As[(kk + 2) * 132 + lr] = av.z;
      As[(kk + 3) * 132 + lr] = av.w;
      Bs[(kk + 0) * 132 + lr] = bv.x;
      Bs[(kk + 1) * 132 + lr] = bv.y;
      Bs[(kk + 2) * 132 + lr] = bv.z;
      Bs[(kk + 3) * 132 + lr] = bv.w;
    }
    __syncthreads();
#pragma unroll
    for (int kk = 0; kk < 16; kk++) {
      float4 a0 = As4[kk * 33 + ty * 2];
      float4 a1 = As4[kk * 33 + ty * 2 + 1];
      float4 b0 = Bs4[kk * 33 + tx];
      float4 b1 = Bs4[kk * 33 + 16 + tx];
      FMA4(c2[0][0], a0.x, b0); FMA4(c2[0][1], a0.x, b1);
      FMA4(c2[1][0], a0.y, b0); FMA4(c2[1][1], a0.y, b1);
      FMA4(c2[2][0], a0.z, b0); FMA4(c2[2][1], a0.z, b1);
      FMA4(c2[3][0], a0.w, b0); FMA4(c2[3][1], a0.w, b1);
      FMA4(c2[4][0], a1.x, b0); FMA4(c2[4][1], a1.x, b1);
      FMA4(c2[5][0], a1.y, b0); FMA4(c2[5][1], a1.y, b1);
      FMA4(c2[6][0], a1.z, b0); FMA4(c2[6][1], a1.z, b1);
      FMA4(c2[7][0], a1.w, b0); FMA4(c2[7][1], a1.w, b1);
    }
  }

  if (n0 < 1024) {
    // q: store straight [i][n]  (n = h*64+d)
#pragma unroll
    for (int a = 0; a < 8; a++) {
      *(float4*)&Q[(size_t)(m0 + ty * 8 + a) * 1024 + n0 + tx * 4]      = c2[a][0];
      *(float4*)&Q[(size_t)(m0 + ty * 8 + a) * 1024 + n0 + 64 + tx * 4] = c2[a][1];
    }
    return;
  }
  if (n0 >= 2048) {
    const int nv0 = n0 - 2048;
#pragma unroll
    for (int a = 0; a < 8; a++) {
      *(float4*)&V[(size_t)(m0 + ty * 8 + a) * 1024 + nv0 + tx * 4]      = c2[a][0];
      *(float4*)&V[(size_t)(m0 + ty * 8 + a) * 1024 + nv0 + 64 + tx * 4] = c2[a][1];
    }
    return;
  }

  // k: transpose 32-col slabs through LDS, store kT[(b*1024+n)*1024 + i]
  const int nt0 = n0 - 1024;
  const int bB = m0 >> 10;
  const int i0 = m0 & 1023;
#pragma unroll
  for (int r = 0; r < 4; r++) {
    __syncthreads();
    if ((tx >> 3) == (r & 1)) {
      const int c0 = (tx & 7) * 4;
#pragma unroll
      for (int a = 0; a < 8; a++) {
        const int m = ty * 8 + a;
        float4 val = c2[a][r >> 1];
        tb[m * 32 + ((c0 + 0 + m) & 31)] = val.x;
        tb[m * 32 + ((c0 + 1 + m) & 31)] = val.y;
        tb[m * 32 + ((c0 + 2 + m) & 31)] = val.z;
        tb[m * 32 + ((c0 + 3 + m) & 31)] = val.w;
      }
    }
    __syncthreads();
    const int nl = t >> 3, mq = t & 7;
    float* Trow = kT + (size_t)(bB * 1024 + nt0 + (r >> 1) * 64 + (r & 1) * 32 + nl) * 1024 + i0;
#pragma unroll
    for (int l = 0; l < 4; l++) {
      const int mb = (l * 8 + mq) * 4;
      float4 o;
      o.x = tb[(mb + 0) * 32 + ((nl + mb + 0) & 31)];
      o.y = tb[(mb + 1) * 32 + ((nl + mb + 1) & 31)];
      o.z = tb[(mb + 2) * 32 + ((nl + mb + 2) & 31)];
      o.w = tb[(mb + 3) * 32 + ((nl + mb + 3) & 31)];
      *(float4*)(Trow + mb) = o;
    }
  }
}

// ---------------------------------------------------------------------------
// K2a v6: l-only stats. grid = b(4) x it(64 x 16i) x jw(16 x 64j) = 4096.
// Wave w handles h in [4w, 4w+4); lane = one j. k[64] in VGPRs per h
// (coalesced dword loads); q rows wave-uniform (scalar loads). No LDS.
// Stores Lp[((b*16+h)*1024+i)*16 + jw] = sum_{j in slice} exp(s).
// ---------------------------------------------------------------------------
__global__ __launch_bounds__(256) void attn_stats_v6(
    const float* __restrict__ Q, const float* __restrict__ kT,
    float* __restrict__ Lp)
{
  const int t  = threadIdx.x;
  const int bx = blockIdx.x;
  const int b  = bx >> 10;
  const int it = (bx >> 4) & 63;
  const int jw = bx & 15;
  const int wv = __builtin_amdgcn_readfirstlane(t >> 6);
  const int l  = t & 63;
  const int i0 = it << 4;
  const int j  = (jw << 6) + l;
  const float scale = 0.03125f;

  float kreg[64];
#pragma unroll 1
  for (int hl = 0; hl < 4; hl++) {
    const int h = wv * 4 + hl;
    const float* kb = kT + (size_t)(b * 1024 + h * 64) * 1024 + j;
#pragma unroll
    for (int d = 0; d < 64; d++) kreg[d] = kb[(size_t)d << 10];

#pragma unroll 1
    for (int ic = 0; ic < 4; ic++) {
      const float* q0 = Q + (size_t)(b * 1024 + i0 + ic * 4) * 1024 + h * 64;
      float a0 = 0.f, a1 = 0.f, a2 = 0.f, a3 = 0.f;
#pragma unroll
      for (int d4 = 0; d4 < 16; d4++) {
        const float4 qa = *(const float4*)(q0 + d4 * 4);
        const float4 qb = *(const float4*)(q0 + 1024 + d4 * 4);
        const float4 qc = *(const float4*)(q0 + 2048 + d4 * 4);
        const float4 qd = *(const float4*)(q0 + 3072 + d4 * 4);
        const float k0 = kreg[d4 * 4 + 0], k1 = kreg[d4 * 4 + 1];
        const float k2 = kreg[d4 * 4 + 2], k3 = kreg[d4 * 4 + 3];
        a0 = fmaf(qa.x, k0, a0); a1 = fmaf(qb.x, k0, a1);
        a2 = fmaf(qc.x, k0, a2); a3 = fmaf(qd.x, k0, a3);
        a0 = fmaf(qa.y, k1, a0); a1 = fmaf(qb.y, k1, a1);
        a2 = fmaf(qc.y, k1, a2); a3 = fmaf(qd.y, k1, a3);
        a0 = fmaf(qa.z, k2, a0); a1 = fmaf(qb.z, k2, a1);
        a2 = fmaf(qc.z, k2, a2); a3 = fmaf(qd.z, k2, a3);
        a0 = fmaf(qa.w, k3, a0); a1 = fmaf(qb.w, k3, a1);
        a2 = fmaf(qc.w, k3, a2); a3 = fmaf(qd.w, k3, a3);
      }
      float e0 = __expf(a0 * scale);
      float e1 = __expf(a1 * scale);
      float e2 = __expf(a2 * scale);
      float e3 = __expf(a3 * scale);
#pragma unroll
      for (int st = 1; st < 64; st <<= 1) {
        e0 += __shfl_xor(e0, st);
        e1 += __shfl_xor(e1, st);
        e2 += __shfl_xor(e2, st);
        e3 += __shfl_xor(e3, st);
      }
      if (l == 0) {
        const int row = (b * 16 + h) * 1024 + i0 + ic * 4;
        Lp[(size_t)(row + 0) * 16 + jw] = e0;
        Lp[(size_t)(row + 1) * 16 + jw] = e1;
        Lp[(size_t)(row + 2) * 16 + jw] = e2;
        Lp[(size_t)(row + 3) * 16 + jw] = e3;
      }
    }
  }
}

// ---------------------------------------------------------------------------
// K2b: Rl = 1 / sum of 16 slice partials (fixed association, deterministic).
// ---------------------------------------------------------------------------
__global__ __launch_bounds__(256) void merge_l(
    const float* __restrict__ Lp, float* __restrict__ Rl)
{
  const int idx = blockIdx.x * 256 + threadIdx.x;   // 65536 rows
  const float4* p = (const float4*)(Lp + (size_t)idx * 16);
  const float4 a = p[0], b4 = p[1], c = p[2], d = p[3];
  const float s = ((((a.x + a.y) + (a.z + a.w)) + ((b4.x + b4.y) + (b4.z + b4.w)))
                 + (((c.x + c.y) + (c.z + c.w)) + ((d.x + d.y) + (d.z + d.w))));
  Rl[idx] = 1.0f / s;
}

// packed key: monotone(float) << 32 | (1023 - j); atomicMax == (>, tie: min j)
__device__ inline unsigned long long mkkey(float v, int j) {
  unsigned u = __float_as_uint(v);
  u = (u & 0x80000000u) ? ~u : (u | 0x80000000u);
  return ((unsigned long long)u << 32) | (unsigned)(1023 - j);
}

// ---------------------------------------------------------------------------
// K2c v6: grid = b(4) x it(64 x 16i) x js(16 x 64j) = 4096 blocks.
// Dot: same k-register/scalar-q engine; p = exp(s)*Rl -> ptile[j*271+i*17+h].
// One barrier. Mix: R5-verified mix/LN/argmax (no rotation) + atomicMax.
// ---------------------------------------------------------------------------
__global__ __launch_bounds__(256) void attn_select_v6(
    const float* __restrict__ Q, const float* __restrict__ kT,
    const float* __restrict__ Rl, const float* __restrict__ Wt,
    const float* __restrict__ ln_g, const float* __restrict__ ln_b,
    unsigned long long* __restrict__ HiKey)
{
  __shared__ __align__(16) float ptile[64 * 271];

  const int t  = threadIdx.x;
  const int bx = blockIdx.x;
  const int b  = bx >> 10;
  const int it = (bx >> 4) & 63;
  const int js = bx & 15;
  const int i0 = it << 4;
  const int j0 = js << 6;
  const int wv = __builtin_amdgcn_readfirstlane(t >> 6);
  const int l  = t & 63;
  const float scale = 0.03125f;

  float kreg[64];
#pragma unroll 1
  for (int hl = 0; hl < 4; hl++) {
    const int h = wv * 4 + hl;
    const float* kb = kT + (size_t)(b * 1024 + h * 64) * 1024 + j0 + l;
#pragma unroll
    for (int d = 0; d < 64; d++) kreg[d] = kb[(size_t)d << 10];

#pragma unroll 1
    for (int ic = 0; ic < 4; ic++) {
      const float* q0 = Q + (size_t)(b * 1024 + i0 + ic * 4) * 1024 + h * 64;
      const float4 rlv = *(const float4*)(Rl + (b * 16 + h) * 1024 + i0 + ic * 4);
      float a0 = 0.f, a1 = 0.f, a2 = 0.f, a3 = 0.f;
#pragma unroll
      for (int d4 = 0; d4 < 16; d4++) {
        const float4 qa = *(const float4*)(q0 + d4 * 4);
        const float4 qb = *(const float4*)(q0 + 1024 + d4 * 4);
        const float4 qc = *(const float4*)(q0 + 2048 + d4 * 4);
        const float4 qd = *(const float4*)(q0 + 3072 + d4 * 4);
        const float k0 = kreg[d4 * 4 + 0], k1 = kreg[d4 * 4 + 1];
        const float k2 = kreg[d4 * 4 + 2], k3 = kreg[d4 * 4 + 3];
        a0 = fmaf(qa.x, k0, a0); a1 = fmaf(qb.x, k0, a1);
        a2 = fmaf(qc.x, k0, a2); a3 = fmaf(qd.x, k0, a3);
        a0 = fmaf(qa.y, k1, a0); a1 = fmaf(qb.y, k1, a1);
        a2 = fmaf(qc.y, k1, a2); a3 = fmaf(qd.y, k1, a3);
        a0 = fmaf(qa.z, k2, a0); a1 = fmaf(qb.z, k2, a1);
        a2 = fmaf(qc.z, k2, a2); a3 = fmaf(qd.z, k2, a3);
        a0 = fmaf(qa.w, k3, a0); a1 = fmaf(qb.w, k3, a1);
        a2 = fmaf(qc.w, k3, a2); a3 = fmaf(qd.w, k3, a3);
      }
      const int iL = ic * 4;
      ptile[l * 271 + (iL + 0) * 17 + h] = __expf(a0 * scale) * rlv.x;
      ptile[l * 271 + (iL + 1) * 17 + h] = __expf(a1 * scale) * rlv.y;
      ptile[l * 271 + (iL + 2) * 17 + h] = __expf(a2 * scale) * rlv.z;
      ptile[l * 271 + (iL + 3) * 17 + h] = __expf(a3 * scale) * rlv.w;
    }
  }
  __syncthreads();

  // ---- mix phase (R5-verified; no rotation) ----
  const int i2 = t >> 4;
  const int g  = (t >> 2) & 3;
  const int hq = t & 3;

  float wtr[4][16], gr[4], br[4];
#pragma unroll
  for (int a = 0; a < 4; a++) {
#pragma unroll
    for (int h2 = 0; h2 < 16; h2++) wtr[a][h2] = Wt[(hq * 4 + a) * 16 + h2];
    gr[a] = ln_g[hq * 4 + a];
    br[a] = ln_b[hq * 4 + a];
  }
  float bv[4]; int bix[4];
#pragma unroll
  for (int a = 0; a < 4; a++) { bv[a] = -1e30f; bix[a] = 0; }

#pragma unroll
  for (int jj = 0; jj < 16; jj++) {
    const int j = g * 16 + jj;
    float pv[16];
#pragma unroll
    for (int h2 = 0; h2 < 16; h2++) pv[h2] = ptile[j * 271 + i2 * 17 + h2];
    float mix[4];
#pragma unroll
    for (int a = 0; a < 4; a++) {
      float s0 = 0.f;
#pragma unroll
      for (int h2 = 0; h2 < 16; h2++) s0 = fmaf(pv[h2], wtr[a][h2], s0);
      mix[a] = s0;
    }
    float s1 = mix[0] + mix[1] + mix[2] + mix[3];
    s1 += __shfl_xor(s1, 1);
    s1 += __shfl_xor(s1, 2);
    const float mu = s1 * 0.0625f;
    float s2 = 0.f;
#pragma unroll
    for (int a = 0; a < 4; a++) { const float dd = mix[a] - mu; s2 = fmaf(dd, dd, s2); }
    s2 += __shfl_xor(s2, 1);
    s2 += __shfl_xor(s2, 2);
    const float rstd = rsqrtf(s2 * 0.0625f + 1e-5f);
    const int jg2 = j0 + j;
#pragma unroll
    for (int a = 0; a < 4; a++) {
      const float nv = (mix[a] - mu) * rstd * gr[a] + br[a];
      if (nv > bv[a]) { bv[a] = nv; bix[a] = jg2; }
    }
  }

#pragma unroll
  for (int a = 0; a < 4; a++) {
    float v = bv[a]; int ix = bix[a];
    {
      const float ov = __shfl_xor(v, 4);
      const int oi = __shfl_xor(ix, 4);
      if (ov > v || (ov == v && oi < ix)) { v = ov; ix = oi; }
    }
    {
      const float ov = __shfl_xor(v, 8);
      const int oi = __shfl_xor(ix, 8);
      if (ov > v || (ov == v && oi < ix)) { v = ov; ix = oi; }
    }
    bv[a] = v; bix[a] = ix;
  }

  if (g == 0) {
#pragma unroll
    for (int a = 0; a < 4; a++) {
      const int cell = (b * 16 + hq * 4 + a) * 1024 + i0 + i2;
      atomicMax(&HiKey[cell], mkkey(bv[a], bix[a]));
    }
  }
}

// ---------------------------------------------------------------------------
// K2d: decode key -> gather V rows (R4/R5-verified).
// ---------------------------------------------------------------------------
__global__ __launch_bounds__(256) void gather_v4(
    const unsigned long long* __restrict__ HiKey, const float* __restrict__ V,
    float* __restrict__ out)
{
  const int t  = threadIdx.x;
  const int bx = blockIdx.x;
  const int b  = bx >> 6;
  const int it = bx & 63;
  const int i2 = t >> 4;
  const int h  = t & 15;

  const unsigned long long key = HiKey[(b * 16 + h) * 1024 + it * 16 + i2];
  const int j = 1023 - (int)(unsigned)(key & 0xFFFFFFFFull);

  const float* vs = V + (size_t)(b * 1024 + j) * 1024 + h * 64;
  float* dst = out + (size_t)(b * 1024 + it * 16 + i2) * 1024 + h * 64;
#pragma unroll
  for (int w = 0; w < 16; w++)
    *(float4*)(dst + w * 4) = *(const float4*)(vs + w * 4);
}

extern "C" void kernel_launch(void* const* d_in, const int* in_sizes, int n_in,
                              void* d_out, int out_size, void* d_ws, size_t ws_size,
                              hipStream_t stream) {
  const float* x   = (const float*)d_in[0];
  const float* Wq  = (const float*)d_in[1];
  const float* Wkv = (const float*)d_in[2];
  const float* Wt  = (const float*)d_in[3];
  const float* lng = (const float*)d_in[4];
  const float* lnb = (const float*)d_in[5];
  float* out = (float*)d_out;
  float* ws  = (float*)d_ws;                          // ~53 MB used
  float* Q  = ws;                                     // 4M f
  float* kT = ws + (size_t)4 * 1024 * 1024;           // 4M f
  float* V  = ws + (size_t)8 * 1024 * 1024;           // 4M f
  float* Lp = ws + (size_t)12 * 1024 * 1024;          // 1M f (64K rows x 16)
  float* Rl = ws + (size_t)13 * 1024 * 1024;          // 64K f
  unsigned long long* HiKey =
      (unsigned long long*)(ws + (size_t)13 * 1024 * 1024 + 131072);  // 64K x 8B

  hipLaunchKernelGGL(qkv_gemm, dim3(24, 32), dim3(256), 0, stream,
                     x, Wq, Wkv, Q, kT, V);
  hipMemsetAsync(HiKey, 0, (size_t)65536 * 8, stream);
  hipLaunchKernelGGL(attn_stats_v6, dim3(4096), dim3(256), 0, stream,
                     Q, kT, Lp);
  hipLaunchKernelGGL(merge_l, dim3(256), dim3(256), 0, stream, Lp, Rl);
  hipLaunchKernelGGL(attn_select_v6, dim3(4096), dim3(256), 0, stream,
                     Q, kT, Rl, Wt, lng, lnb, HiKey);
  hipLaunchKernelGGL(gather_v4, dim3(256), dim3(256), 0, stream,
                     HiKey, V, out);
}